// Round 12
// baseline (105.983 us; speedup 1.0000x reference)
//
#include <hip/hip_runtime.h>
#include <stdint.h>

// HammingDistance via bit-plane packing.
// Codes 0..7 = 3 bits. Pack bit-plane b of 32 consecutive d's into one u32.
// mismatch(32 elems) = popc((x0^y0)|(x1^y1)|(x2^y2))
// out[n,m] = total_mismatch / 256 (exact, pow2).
//
// R12 = R5 with ONE change: b-fragment reads split b128 -> b64({p0,p1}) +
// b32(p2) with per-column in-slot rotation (cols 64..127 store {p2,X,p0,p1})
// so the two lanes sharing a swizzle slot read at word offsets 0 vs 2 ->
// 16 b64 reads cover all 32 banks, 16 b32 reads hit 16 distinct banks:
// conflict-free by construction. Tests the "b128 2-way bank-group aliasing
// costs 2x" theory for the 104us plateau. Also drops b regs 32->24.

#define D_    256
#define GRP   8          // 32-element groups per row
#define RWORD 32         // padded u32 per packed row (8 groups * 4)
#define BM    128
#define BN    128

__global__ __launch_bounds__(256) void pack_planes_kernel(
    const float* __restrict__ in, uint32_t* __restrict__ out, int total)
{
    int idx = blockIdx.x * blockDim.x + threadIdx.x;   // one (row, group) each
    if (idx >= total) return;
    int row = idx >> 3, g = idx & 7;
    const float* p = in + (size_t)row * D_ + g * 32;
    uint32_t b0 = 0, b1 = 0, b2 = 0;
#pragma unroll
    for (int d = 0; d < 32; d += 4) {
        float4 f = *(const float4*)(p + d);
        uint32_t c0 = (uint32_t)f.x, c1 = (uint32_t)f.y;
        uint32_t c2 = (uint32_t)f.z, c3 = (uint32_t)f.w;
        b0 |= ((c0 & 1) << d) | ((c1 & 1) << (d + 1)) |
              ((c2 & 1) << (d + 2)) | ((c3 & 1) << (d + 3));
        b1 |= (((c0 >> 1) & 1) << d) | (((c1 >> 1) & 1) << (d + 1)) |
              (((c2 >> 1) & 1) << (d + 2)) | (((c3 >> 1) & 1) << (d + 3));
        b2 |= (((c0 >> 2) & 1) << d) | (((c1 >> 2) & 1) << (d + 1)) |
              (((c2 >> 2) & 1) << (d + 2)) | (((c3 >> 2) & 1) << (d + 3));
    }
    uint4 v; v.x = b0; v.y = b1; v.z = b2; v.w = 0;
    *(uint4*)&out[(size_t)row * RWORD + g * 4] = v;
}

__global__ __launch_bounds__(256) void hamming_planes_kernel(
    const uint32_t* __restrict__ Xp, const uint32_t* __restrict__ Yp,
    float* __restrict__ out, int Mcols)
{
    // slot = g ^ ((row>>3)&7). a-reads: 4 distinct addrs, broadcast, free.
    // b-reads: split b64+b32 with rotation -> conflict-free (see header).
    __shared__ __align__(16) uint4 As4[BM * GRP];
    __shared__ __align__(16) uint4 Bs4[BN * GRP];

    const int tid = threadIdx.x;
    const int tn = tid & 15;          // 16 col-threads (cols tn*8..tn*8+7)
    const int tm = tid >> 4;          // 16 row-threads (rows tm*8..tm*8+7)
    const int rowBase = blockIdx.y * BM;
    const int colBase = blockIdx.x * BN;

    // ---- load phase: 1024 uint4 per array, 4 per thread, lane-contiguous ----
    const uint4* Xg = (const uint4*)(Xp + (size_t)rowBase * RWORD);
    const uint4* Yg = (const uint4*)(Yp + (size_t)colBase * RWORD);
#pragma unroll
    for (int i = 0; i < 4; ++i) {
        int f = i * 256 + tid;               // flat (row*8 + g)
        int swz = (f & ~7) | ((f & 7) ^ ((f >> 6) & 7));
        As4[swz] = Xg[f];
        uint4 v = Yg[f];
        if ((f >> 9) & 1) {                  // rows 64..127: rotate {p2,X,p0,p1}
            uint4 w; w.x = v.z; w.y = v.w; w.z = v.x; w.w = v.y; v = w;
        }
        Bs4[swz] = v;
    }
    __syncthreads();

    // cnt[i][jp]: low16 = column 2*jp, high16 = column 2*jp+1
    uint32_t cnt[8][4] = {};

    const int rot = tn >> 3;                     // 0 (cols<64) / 1 (cols>=64)
    const uint32_t* BsW = (const uint32_t*)Bs4;

#pragma unroll 1
    for (int g = 0; g < GRP; ++g) {
        const int sa = (g ^ tm) & 7;
        const int sb = (g ^ tn) & 7;
        uint2 blo[8]; uint32_t bp2[8];
#pragma unroll
        for (int j = 0; j < 8; ++j) {
            int bw = ((tn * 8 + j) * 8 + sb) * 4;          // word index of slot
            blo[j] = *(const uint2*)&BsW[bw + 2 * rot];    // {p0,p1}
            bp2[j] = BsW[bw + 2 - 2 * rot];                // p2
        }
#pragma unroll
        for (int i = 0; i < 8; ++i) {
            uint4 a = As4[(tm * 8 + i) * 8 + sa];
#pragma unroll
            for (int jp = 0; jp < 4; ++jp) {
                uint32_t ue = (a.x ^ blo[2 * jp].x) | (a.y ^ blo[2 * jp].y) |
                              (a.z ^ bp2[2 * jp]);
                uint32_t uo = (a.x ^ blo[2 * jp + 1].x) |
                              (a.y ^ blo[2 * jp + 1].y) |
                              (a.z ^ bp2[2 * jp + 1]);
                cnt[i][jp] += __popc(ue) + (__popc(uo) << 16);
            }
        }
    }

    const float inv = 1.0f / (float)D_;     // out = mismatches / 256
#pragma unroll
    for (int i = 0; i < 8; ++i) {
        float* orow = &out[(size_t)(rowBase + tm * 8 + i) * Mcols + colBase + tn * 8];
        float4 r0, r1;
        r0.x = (float)(cnt[i][0] & 0xffffu) * inv;
        r0.y = (float)(cnt[i][0] >> 16) * inv;
        r0.z = (float)(cnt[i][1] & 0xffffu) * inv;
        r0.w = (float)(cnt[i][1] >> 16) * inv;
        r1.x = (float)(cnt[i][2] & 0xffffu) * inv;
        r1.y = (float)(cnt[i][2] >> 16) * inv;
        r1.z = (float)(cnt[i][3] & 0xffffu) * inv;
        r1.w = (float)(cnt[i][3] >> 16) * inv;
        *(float4*)(orow + 0) = r0;
        *(float4*)(orow + 4) = r1;
    }
}

// ---------------- fallback (ws too small): fused one-hot kernel ----------------
__device__ __forceinline__ uint32_t pack4_oh(const float* p) {
    float4 f = *(const float4*)p;
    return (1u << (int)f.x) | ((1u << (int)f.y) << 8) |
           ((1u << (int)f.z) << 16) | ((1u << (int)f.w) << 24);
}

__global__ __launch_bounds__(256) void hamming_fallback_kernel(
    const float* __restrict__ X, const float* __restrict__ Y,
    float* __restrict__ out, int Mcols)
{
    __shared__ uint32_t As[16][64];
    __shared__ uint32_t Bs[16][64];
    const int tid = threadIdx.x;
    const int tn = tid & 15, tm = tid >> 4;
    const int rowBase = blockIdx.y * 64, colBase = blockIdx.x * 64;
    const int lrow = tid >> 2, lw4 = (tid & 3) * 4;
    uint32_t cnt[4][4] = {};
    for (int k0 = 0; k0 < 64; k0 += 16) {
        uint4 av, bv;
        const float* px = X + (size_t)(rowBase + lrow) * D_ + (size_t)(k0 + lw4) * 4;
        const float* py = Y + (size_t)(colBase + lrow) * D_ + (size_t)(k0 + lw4) * 4;
        av.x = pack4_oh(px + 0);  av.y = pack4_oh(px + 4);
        av.z = pack4_oh(px + 8);  av.w = pack4_oh(px + 12);
        bv.x = pack4_oh(py + 0);  bv.y = pack4_oh(py + 4);
        bv.z = pack4_oh(py + 8);  bv.w = pack4_oh(py + 12);
        __syncthreads();
        As[lw4 + 0][lrow] = av.x;  As[lw4 + 1][lrow] = av.y;
        As[lw4 + 2][lrow] = av.z;  As[lw4 + 3][lrow] = av.w;
        Bs[lw4 + 0][lrow] = bv.x;  Bs[lw4 + 1][lrow] = bv.y;
        Bs[lw4 + 2][lrow] = bv.z;  Bs[lw4 + 3][lrow] = bv.w;
        __syncthreads();
#pragma unroll
        for (int k = 0; k < 16; ++k) {
            uint4 a4 = *(const uint4*)&As[k][tm * 4];
            uint4 b4 = *(const uint4*)&Bs[k][tn * 4];
            uint32_t a[4] = {a4.x, a4.y, a4.z, a4.w};
            uint32_t b[4] = {b4.x, b4.y, b4.z, b4.w};
#pragma unroll
            for (int i = 0; i < 4; ++i)
#pragma unroll
                for (int j = 0; j < 4; ++j)
                    cnt[i][j] += __popc(a[i] & b[j]);
        }
    }
    const float inv = 1.0f / (float)D_;
#pragma unroll
    for (int i = 0; i < 4; ++i) {
        float4 r;
        r.x = 1.0f - (float)cnt[i][0] * inv;
        r.y = 1.0f - (float)cnt[i][1] * inv;
        r.z = 1.0f - (float)cnt[i][2] * inv;
        r.w = 1.0f - (float)cnt[i][3] * inv;
        *(float4*)&out[(size_t)(rowBase + tm * 4 + i) * Mcols + colBase + tn * 4] = r;
    }
}

extern "C" void kernel_launch(void* const* d_in, const int* in_sizes, int n_in,
                              void* d_out, int out_size, void* d_ws, size_t ws_size,
                              hipStream_t stream) {
    const float* x = (const float*)d_in[0];
    const float* y = (const float*)d_in[1];
    float* out = (float*)d_out;
    const int N = in_sizes[0] / D_;
    const int M = in_sizes[1] / D_;

    const size_t need = ((size_t)N + (size_t)M) * RWORD * sizeof(uint32_t);
    if (ws_size >= need) {
        uint32_t* Xp = (uint32_t*)d_ws;
        uint32_t* Yp = Xp + (size_t)N * RWORD;
        int xt = N * GRP, yt = M * GRP;
        pack_planes_kernel<<<(xt + 255) / 256, 256, 0, stream>>>(x, Xp, xt);
        pack_planes_kernel<<<(yt + 255) / 256, 256, 0, stream>>>(y, Yp, yt);
        dim3 grid(M / BN, N / BM);
        hamming_planes_kernel<<<grid, 256, 0, stream>>>(Xp, Yp, out, M);
    } else {
        dim3 grid(M / 64, N / 64);
        hamming_fallback_kernel<<<grid, 256, 0, stream>>>(x, y, out, M);
    }
}

// Round 13
// 103.673 us; speedup vs baseline: 1.0223x; 1.0223x over previous
//
#include <hip/hip_runtime.h>
#include <stdint.h>

// HammingDistance via bit-plane packing.  == FINAL: R5 configuration ==
// (verified 104.2us R5, 104.1us R11 restoration; absmax 0)
//
// Codes 0..7 = 3 bits. Pack bit-plane b of 32 consecutive d's into one u32.
// mismatch(32 elems) = popc((x0^y0)|(x1^y1)|(x2^y2))
// out[n,m] = total_mismatch / 256 (exact, pow2).
//
// Probed and closed (R6-R12): asm-pinned accumulate (null), 256x128 tile
// (VGPR cliff), b-double-buffer (VGPR cliff), vec3/b96 reads (negative),
// column pass-split (flat), conflict-free split b64+b32 b-reads (flat).
// Structural constraint: ~40us VALU + ~41us LDS pipe + 43us HBM store,
// imperfectly overlapped at 3 waves/SIMD (pinned by the 64-count
// accumulator working set) -> ~104us plateau = this formulation's roofline.

#define D_    256
#define GRP   8          // 32-element groups per row
#define RWORD 32         // padded u32 per packed row (8 groups * 4)
#define BM    128
#define BN    128

__global__ __launch_bounds__(256) void pack_planes_kernel(
    const float* __restrict__ in, uint32_t* __restrict__ out, int total)
{
    int idx = blockIdx.x * blockDim.x + threadIdx.x;   // one (row, group) each
    if (idx >= total) return;
    int row = idx >> 3, g = idx & 7;
    const float* p = in + (size_t)row * D_ + g * 32;
    uint32_t b0 = 0, b1 = 0, b2 = 0;
#pragma unroll
    for (int d = 0; d < 32; d += 4) {
        float4 f = *(const float4*)(p + d);
        uint32_t c0 = (uint32_t)f.x, c1 = (uint32_t)f.y;
        uint32_t c2 = (uint32_t)f.z, c3 = (uint32_t)f.w;
        b0 |= ((c0 & 1) << d) | ((c1 & 1) << (d + 1)) |
              ((c2 & 1) << (d + 2)) | ((c3 & 1) << (d + 3));
        b1 |= (((c0 >> 1) & 1) << d) | (((c1 >> 1) & 1) << (d + 1)) |
              (((c2 >> 1) & 1) << (d + 2)) | (((c3 >> 1) & 1) << (d + 3));
        b2 |= (((c0 >> 2) & 1) << d) | (((c1 >> 2) & 1) << (d + 1)) |
              (((c2 >> 2) & 1) << (d + 2)) | (((c3 >> 2) & 1) << (d + 3));
    }
    uint4 v; v.x = b0; v.y = b1; v.z = b2; v.w = 0;
    *(uint4*)&out[(size_t)row * RWORD + g * 4] = v;
}

__global__ __launch_bounds__(256) void hamming_planes_kernel(
    const uint32_t* __restrict__ Xp, const uint32_t* __restrict__ Yp,
    float* __restrict__ out, int Mcols)
{
    // slot = g ^ ((row>>3)&7): b-reads land 2-way (free), a-reads broadcast.
    __shared__ __align__(16) uint4 As4[BM * GRP];
    __shared__ __align__(16) uint4 Bs4[BN * GRP];

    const int tid = threadIdx.x;
    const int tn = tid & 15;          // 16 col-threads
    const int tm = tid >> 4;          // 16 row-threads
    const int rowBase = blockIdx.y * BM;
    const int colBase = blockIdx.x * BN;

    // ---- load phase: 1024 uint4 per array, 4 per thread, lane-contiguous ----
    const uint4* Xg = (const uint4*)(Xp + (size_t)rowBase * RWORD);
    const uint4* Yg = (const uint4*)(Yp + (size_t)colBase * RWORD);
#pragma unroll
    for (int i = 0; i < 4; ++i) {
        int f = i * 256 + tid;               // flat (row*8 + g)
        int swz = (f & ~7) | ((f & 7) ^ ((f >> 6) & 7));
        As4[swz] = Xg[f];
        Bs4[swz] = Yg[f];
    }
    __syncthreads();

    // cnt[i][jp]: low16 = column 2*jp, high16 = column 2*jp+1
    uint32_t cnt[8][4] = {};

#pragma unroll 1
    for (int g = 0; g < GRP; ++g) {
        const int sa = (g ^ tm) & 7;
        const int sb = (g ^ tn) & 7;
        uint4 b[8];
#pragma unroll
        for (int j = 0; j < 8; ++j) b[j] = Bs4[(tn * 8 + j) * 8 + sb];
#pragma unroll
        for (int i = 0; i < 8; ++i) {
            uint4 a = As4[(tm * 8 + i) * 8 + sa];
#pragma unroll
            for (int jp = 0; jp < 4; ++jp) {
                uint32_t ue = (a.x ^ b[2 * jp].x) | (a.y ^ b[2 * jp].y) |
                              (a.z ^ b[2 * jp].z);
                uint32_t uo = (a.x ^ b[2 * jp + 1].x) | (a.y ^ b[2 * jp + 1].y) |
                              (a.z ^ b[2 * jp + 1].z);
                cnt[i][jp] += __popc(ue) + (__popc(uo) << 16);
            }
        }
    }

    const float inv = 1.0f / (float)D_;     // out = mismatches / 256
#pragma unroll
    for (int i = 0; i < 8; ++i) {
        float* orow = &out[(size_t)(rowBase + tm * 8 + i) * Mcols + colBase + tn * 8];
        float4 r0, r1;
        r0.x = (float)(cnt[i][0] & 0xffffu) * inv;
        r0.y = (float)(cnt[i][0] >> 16) * inv;
        r0.z = (float)(cnt[i][1] & 0xffffu) * inv;
        r0.w = (float)(cnt[i][1] >> 16) * inv;
        r1.x = (float)(cnt[i][2] & 0xffffu) * inv;
        r1.y = (float)(cnt[i][2] >> 16) * inv;
        r1.z = (float)(cnt[i][3] & 0xffffu) * inv;
        r1.w = (float)(cnt[i][3] >> 16) * inv;
        *(float4*)(orow + 0) = r0;
        *(float4*)(orow + 4) = r1;
    }
}

// ---------------- fallback (ws too small): fused one-hot kernel ----------------
__device__ __forceinline__ uint32_t pack4_oh(const float* p) {
    float4 f = *(const float4*)p;
    return (1u << (int)f.x) | ((1u << (int)f.y) << 8) |
           ((1u << (int)f.z) << 16) | ((1u << (int)f.w) << 24);
}

__global__ __launch_bounds__(256) void hamming_fallback_kernel(
    const float* __restrict__ X, const float* __restrict__ Y,
    float* __restrict__ out, int Mcols)
{
    __shared__ uint32_t As[16][64];
    __shared__ uint32_t Bs[16][64];
    const int tid = threadIdx.x;
    const int tn = tid & 15, tm = tid >> 4;
    const int rowBase = blockIdx.y * 64, colBase = blockIdx.x * 64;
    const int lrow = tid >> 2, lw4 = (tid & 3) * 4;
    uint32_t cnt[4][4] = {};
    for (int k0 = 0; k0 < 64; k0 += 16) {
        uint4 av, bv;
        const float* px = X + (size_t)(rowBase + lrow) * D_ + (size_t)(k0 + lw4) * 4;
        const float* py = Y + (size_t)(colBase + lrow) * D_ + (size_t)(k0 + lw4) * 4;
        av.x = pack4_oh(px + 0);  av.y = pack4_oh(px + 4);
        av.z = pack4_oh(px + 8);  av.w = pack4_oh(px + 12);
        bv.x = pack4_oh(py + 0);  bv.y = pack4_oh(py + 4);
        bv.z = pack4_oh(py + 8);  bv.w = pack4_oh(py + 12);
        __syncthreads();
        As[lw4 + 0][lrow] = av.x;  As[lw4 + 1][lrow] = av.y;
        As[lw4 + 2][lrow] = av.z;  As[lw4 + 3][lrow] = av.w;
        Bs[lw4 + 0][lrow] = bv.x;  Bs[lw4 + 1][lrow] = bv.y;
        Bs[lw4 + 2][lrow] = bv.z;  Bs[lw4 + 3][lrow] = bv.w;
        __syncthreads();
#pragma unroll
        for (int k = 0; k < 16; ++k) {
            uint4 a4 = *(const uint4*)&As[k][tm * 4];
            uint4 b4 = *(const uint4*)&Bs[k][tn * 4];
            uint32_t a[4] = {a4.x, a4.y, a4.z, a4.w};
            uint32_t b[4] = {b4.x, b4.y, b4.z, b4.w};
#pragma unroll
            for (int i = 0; i < 4; ++i)
#pragma unroll
                for (int j = 0; j < 4; ++j)
                    cnt[i][j] += __popc(a[i] & b[j]);
        }
    }
    const float inv = 1.0f / (float)D_;
#pragma unroll
    for (int i = 0; i < 4; ++i) {
        float4 r;
        r.x = 1.0f - (float)cnt[i][0] * inv;
        r.y = 1.0f - (float)cnt[i][1] * inv;
        r.z = 1.0f - (float)cnt[i][2] * inv;
        r.w = 1.0f - (float)cnt[i][3] * inv;
        *(float4*)&out[(size_t)(rowBase + tm * 4 + i) * Mcols + colBase + tn * 4] = r;
    }
}

extern "C" void kernel_launch(void* const* d_in, const int* in_sizes, int n_in,
                              void* d_out, int out_size, void* d_ws, size_t ws_size,
                              hipStream_t stream) {
    const float* x = (const float*)d_in[0];
    const float* y = (const float*)d_in[1];
    float* out = (float*)d_out;
    const int N = in_sizes[0] / D_;
    const int M = in_sizes[1] / D_;

    const size_t need = ((size_t)N + (size_t)M) * RWORD * sizeof(uint32_t);
    if (ws_size >= need) {
        uint32_t* Xp = (uint32_t*)d_ws;
        uint32_t* Yp = Xp + (size_t)N * RWORD;
        int xt = N * GRP, yt = M * GRP;
        pack_planes_kernel<<<(xt + 255) / 256, 256, 0, stream>>>(x, Xp, xt);
        pack_planes_kernel<<<(yt + 255) / 256, 256, 0, stream>>>(y, Yp, yt);
        dim3 grid(M / BN, N / BM);
        hamming_planes_kernel<<<grid, 256, 0, stream>>>(Xp, Yp, out, M);
    } else {
        dim3 grid(M / 64, N / 64);
        hamming_fallback_kernel<<<grid, 256, 0, stream>>>(x, y, out, M);
    }
}